// Round 7
// baseline (29.207 us; speedup 1.0000x reference)
//
#include <hip/hip_runtime.h>

#define LN 8192           // 8194 - 2
#define B_ROWS 4096
#define NMEANS 6

#define NBLOCKS 2048
#define NTHREADS 256
// One "sweep" = whole grid's v4f stores = 2048*256*4 floats = 8 MiB = 256 rows.
// 8 MiB is a multiple of the 32 KB row, so each thread's column is invariant
// across sweeps -> compute once, store 16x, fully linear global write stream.
#define SWEEP_FLOATS (NBLOCKS * NTHREADS * 4)   // 2,097,152
#define NSWEEPS 16                              // 16 * 256 rows = 4096

typedef float v4f __attribute__((ext_vector_type(4)));

// ---------------------------------------------------------------------------
// row[j] = exp(-0.5u^2) * Horner_k( w_k*norm*e^(-0.5k^2), E=e^u ), u = 5j/8192
// Linear streaming store pattern (fillBuffer-isomorphic): the whole grid
// writes one contiguous 8 MiB window per sweep; per-thread stores stride
// 8 MiB. Store count and compute identical to the tiled R6 kernel — only the
// address mapping changed.
// ---------------------------------------------------------------------------
__global__ void __launch_bounds__(256)
fused_kernel(const float* __restrict__ w, float* __restrict__ out) {
    const int tid = blockIdx.x * NTHREADS + threadIdx.x;
    const int j0  = (tid * 4) & (LN - 1);   // column of this thread's v4f

    // norm * exp(-0.5*k^2), k = 0..5  (norm = 1/(0.2*sqrt(2*pi)))
    const float bk[NMEANS] = {1.99471140f, 1.20985428f, 0.26995483f,
                              0.02215925f, 6.69151e-4f, 7.43360e-6f};
    float a[NMEANS];
#pragma unroll
    for (int k = 0; k < NMEANS; ++k) a[k] = w[k] * bk[k];

    v4f v;
#pragma unroll
    for (int e = 0; e < 4; ++e) {
        float u = (float)(j0 + e) * (5.0f / (float)LN);  // 5 * pos
        float g = __expf(-0.5f * u * u);
        float E = __expf(u);
        float h = a[5];
        h = h * E + a[4];
        h = h * E + a[3];
        h = h * E + a[2];
        h = h * E + a[1];
        h = h * E + a[0];
        v[e] = g * h;
    }

    // 16 linear sweeps: whole grid streams contiguously, 8 MiB per sweep
    float* base = out + (long long)tid * 4;
#pragma unroll
    for (int s = 0; s < NSWEEPS; ++s) {
        *(v4f*)(base + (long long)s * SWEEP_FLOATS) = v;
    }
}

extern "C" void kernel_launch(void* const* d_in, const int* in_sizes, int n_in,
                              void* d_out, int out_size, void* d_ws, size_t ws_size,
                              hipStream_t stream) {
    const float* w = (const float*)d_in[0];   // weights [6]
    // d_in[1] (inp) is shape-only in the reference -> never read.
    float* out = (float*)d_out;

    fused_kernel<<<dim3(NBLOCKS), dim3(NTHREADS), 0, stream>>>(w, out);
}

// Round 8
// 26.024 us; speedup vs baseline: 1.1223x; 1.1223x over previous
//
#include <hip/hip_runtime.h>

#define LN 8192           // 8194 - 2
#define B_ROWS 4096
#define NMEANS 6

#define COLS_PER_BLOCK 1024   // 256 threads * 4 floats
#define ROWS_PER_BLOCK 64
#define COL_SEGS (LN / COLS_PER_BLOCK)        // 8
#define ROW_CHUNKS (B_ROWS / ROWS_PER_BLOCK)  // 64
// grid = 8 * 64 = 512 blocks (2 per CU) — 4x fewer workgroups to dispatch,
// 4x more stores per thread to amortize prologue + ramp.

typedef float v4f __attribute__((ext_vector_type(4)));

// ---------------------------------------------------------------------------
// row[j] = exp(-0.5u^2) * Horner_k( w_k*norm*e^(-0.5k^2), E=e^u ), u = 5j/8192
// Tiled store pattern (proven best: R6 26.1 µs vs linear-sweep 29.2 µs).
// Each block owns a 64-row x 1024-col tile; each thread computes one v4f
// column value once and streams it to 64 rows with plain stores.
// ---------------------------------------------------------------------------
__global__ void __launch_bounds__(256)
fused_kernel(const float* __restrict__ w, float* __restrict__ out) {
    const int bid     = blockIdx.x;
    const int colSeg  = bid & (COL_SEGS - 1);        // 0..7
    const int rowBase = (bid >> 3) * ROWS_PER_BLOCK; // 0..4032 step 64

    const int j0 = colSeg * COLS_PER_BLOCK + threadIdx.x * 4;

    // norm * exp(-0.5*k^2), k = 0..5  (norm = 1/(0.2*sqrt(2*pi)))
    const float bk[NMEANS] = {1.99471140f, 1.20985428f, 0.26995483f,
                              0.02215925f, 6.69151e-4f, 7.43360e-6f};
    float a[NMEANS];
#pragma unroll
    for (int k = 0; k < NMEANS; ++k) a[k] = w[k] * bk[k];

    v4f v;
#pragma unroll
    for (int e = 0; e < 4; ++e) {
        float u = (float)(j0 + e) * (5.0f / (float)LN);  // 5 * pos
        float g = __expf(-0.5f * u * u);
        float E = __expf(u);
        float h = a[5];
        h = h * E + a[4];
        h = h * E + a[3];
        h = h * E + a[2];
        h = h * E + a[1];
        h = h * E + a[0];
        v[e] = g * h;
    }

    // stream the tile: 64 rows, fully-coalesced 1 KiB/wave plain stores
    float* base = out + (long long)rowBase * LN + j0;
#pragma unroll
    for (int r = 0; r < ROWS_PER_BLOCK; ++r) {
        *(v4f*)(base + (long long)r * LN) = v;
    }
}

extern "C" void kernel_launch(void* const* d_in, const int* in_sizes, int n_in,
                              void* d_out, int out_size, void* d_ws, size_t ws_size,
                              hipStream_t stream) {
    const float* w = (const float*)d_in[0];   // weights [6]
    // d_in[1] (inp) is shape-only in the reference -> never read.
    float* out = (float*)d_out;

    fused_kernel<<<dim3(COL_SEGS * ROW_CHUNKS), dim3(256), 0, stream>>>(w, out);
}